// Round 14
// baseline (251.611 us; speedup 1.0000x reference)
//
#include <hip/hip_runtime.h>
#include <math.h>

typedef int v4i  __attribute__((ext_vector_type(4)));
typedef int v16i __attribute__((ext_vector_type(16)));

#define DIM 4096
#define BM 256              // output tile (BM x BM)
#define BK 64               // K-tile bytes (int8)
#define ATILE (BM * BK)     // 16384 B per operand tile
#define BUFSZ (2 * ATILE)   // 32768 B per buffer (A | B)

// ---------------------------------------------------------------------------
// async global->LDS 16B copy (wave-uniform base + lane*16 destination rule)
// ---------------------------------------------------------------------------
__device__ __forceinline__ void async16(const void* g, void* l) {
    __builtin_amdgcn_global_load_lds((__attribute__((address_space(1))) void*)(g),
                                     (__attribute__((address_space(3))) void*)(l),
                                     16, 0, 0);
}

// raw barrier / counted waitcnt (T4): no implicit vmcnt(0) drain.
#define VMCNT(N) asm volatile("s_waitcnt vmcnt(" #N ")" ::: "memory")
#define BARRIER() asm volatile("s_barrier" ::: "memory")

// ---------------------------------------------------------------------------
// Fused prep (passed R10/R11/R13): FWHT(256)+quant via rinv multiply;
// weight narrowing int32->int8.
// ---------------------------------------------------------------------------
__global__ __launch_bounds__(256) void prep(const float* __restrict__ x,
                                            const int* __restrict__ w,
                                            signed char* __restrict__ q,
                                            signed char* __restrict__ w8,
                                            float* __restrict__ scales) {
    if (blockIdx.x >= 4096) {
        int i = (blockIdx.x - 4096) * 256 + threadIdx.x;
        int4 v = ((const int4*)w)[i];
        char4 c;
        c.x = (signed char)v.x; c.y = (signed char)v.y;
        c.z = (signed char)v.z; c.w = (signed char)v.w;
        ((char4*)w8)[i] = c;
        return;
    }
    const int row  = blockIdx.x;
    const int lane = threadIdx.x & 63;
    const int wave = threadIdx.x >> 6;
    const float4* xr4 = (const float4*)(x + (size_t)row * DIM);

    float sgn[6];
    #pragma unroll
    for (int i = 0; i < 6; ++i) sgn[i] = (lane & (1 << i)) ? -1.0f : 1.0f;

    float f[4][4];                      // UNSCALED FWHT values (x 16 vs ref)
    #pragma unroll
    for (int b = 0; b < 4; ++b) {
        const int blk = wave + 4 * b;
        float4 v = xr4[blk * 64 + lane];
        float t0 = v.x + v.y, t1 = v.x - v.y;
        float t2 = v.z + v.w, t3 = v.z - v.w;
        f[b][0] = t0 + t2; f[b][1] = t1 + t3;
        f[b][2] = t0 - t2; f[b][3] = t1 - t3;
        #pragma unroll
        for (int st = 0; st < 6; ++st) {
            const int m = 1 << st;
            #pragma unroll
            for (int j = 0; j < 4; ++j) {
                float p = __shfl_xor(f[b][j], m, 64);
                f[b][j] = fmaf(sgn[st], f[b][j], p);
            }
        }
    }

    float m = 0.0f;
    #pragma unroll
    for (int b = 0; b < 4; ++b)
        #pragma unroll
        for (int j = 0; j < 4; ++j) m = fmaxf(m, fabsf(f[b][j]));
    #pragma unroll
    for (int d = 32; d; d >>= 1) m = fmaxf(m, __shfl_xor(m, d, 64));
    __shared__ float sm[4];
    if (lane == 0) sm[wave] = m;
    __syncthreads();
    m = fmaxf(fmaxf(sm[0], sm[1]), fmaxf(sm[2], sm[3]));

    const float s = (m * 0.0625f) / 7.0f;   // identical value to verified ver.
    if (threadIdx.x == 0) scales[row] = s;
    const float rinv = 7.0f / m;            // quant reciprocal (unscaled dom.)

    char4* qr4 = (char4*)(q + (size_t)row * DIM);
    #pragma unroll
    for (int b = 0; b < 4; ++b) {
        const int blk = wave + 4 * b;
        char4 c;
        int qi;
        qi = (int)rintf(f[b][0] * rinv); c.x = (signed char)min(7, max(-8, qi));
        qi = (int)rintf(f[b][1] * rinv); c.y = (signed char)min(7, max(-8, qi));
        qi = (int)rintf(f[b][2] * rinv); c.z = (signed char)min(7, max(-8, qi));
        qi = (int)rintf(f[b][3] * rinv); c.w = (signed char)min(7, max(-8, qi));
        qr4[blk * 64 + lane] = c;
    }
}

// ---------------------------------------------------------------------------
// int8 GEMM, 256x256 tile, BK=64, 8 waves (2M x 4N), quad-buffered LDS.
// R10 staging skeleton (best: 86.7us) + two new levers:
//
// 1) FRAGMENT-ORDER LDS LAYOUT: each (rowgroup g, k-half s) 1KB block is
//    stored in exact MFMA lane order (slot l = row g*32+(l&31), kbytes
//    32s+16*(l>>5)).  The DMA *source* address is pre-permuted (dest stays
//    linear, as global_load_lds requires); reads become base+lane*16+imm
//    (frees 12 offset VGPRs, canonical sequential bank pattern).
//    Data read is bit-identical to the passing R10/R13 kernels.
//
// 2) FRAGMENT SOFTWARE PIPELINE (the convoy-breaker): R10-R13 all convoy:
//    all waves ds_read at the barrier (port drains ~1536 cyc, matrix idle)
//    then all MFMA (~1171 cyc, port idle) -> 3251 cyc/tile, MfmaUtil 33%.
//    Now per substep t: read s1-frags(t) at top (hide under s0-MFMAs);
//    read s0-frags(t+1) mid-substep (tile t+1 is provably visible:
//    VMCNT(4)+barrier with 3-deep staging) placed AFTER the last s0(t)
//    MFMA so the allocator reuses the same registers -> zero extra VGPR.
//    Port time now overlaps matrix time within each wave.
// ---------------------------------------------------------------------------
__global__ __launch_bounds__(512, 2) void gemm_q8(const signed char* __restrict__ A,
                                                  const signed char* __restrict__ B,
                                                  const float* __restrict__ rowScale,
                                                  const float* __restrict__ wscale,
                                                  const float* __restrict__ bias,
                                                  float* __restrict__ out) {
    __shared__ __align__(16) signed char S[4 * BUFSZ];   // 128 KB

    // XCD swizzle: 256 blocks -> each XCD a 4(bm) x 8(bn) rectangle.
    const int flat = blockIdx.y * gridDim.x + blockIdx.x;
    const int xcd  = flat & 7;
    const int idx  = flat >> 3;                 // 0..31
    const int bm   = ((xcd >> 1) << 2) + (idx & 3);
    const int bn   = ((xcd & 1) << 3) + (idx >> 2);

    const int t = threadIdx.x;
    const int lane = t & 63;
    const int wave = t >> 6;                    // 0..7
    const int wm = (wave >> 2) * 128;           // 2 waves in M
    const int wn = (wave & 3) * 64;             // 4 waves in N
    const int l31 = lane & 31, lh = lane >> 5;

    // --- staging: thread t fills fragment slots cidx = t, t+512 of each
    // operand tile.  Fragment-order source: slot cidx -> block b = cidx>>6
    // (g = b>>1 rowgroup, s = b&1 k-half), l = cidx&63 ->
    // row g*32+(l&31), kbytes 32s+16*(l>>5).  LDS dest stays linear.
    const signed char* ga[2];
    const signed char* gb[2];
    int ldsA[2], ldsB[2];
    #pragma unroll
    for (int h = 0; h < 2; ++h) {
        const int cidx = t + 512 * h;           // 0..1023
        const int b    = cidx >> 6;             // 0..15
        const int g    = b >> 1;                // rowgroup / colgroup
        const int sH   = b & 1;                 // k-half
        const int l    = cidx & 63;
        const int row  = g * 32 + (l & 31);
        const int kb   = sH * 32 + (l >> 5) * 16;
        ga[h] = A + (size_t)(bm * BM + row) * DIM + kb;
        gb[h] = B + (size_t)(bn * BM + row) * DIM + kb;
        ldsA[h] = cidx * 16;                    // linear LDS dest (A region)
        ldsB[h] = ATILE + cidx * 16;            // linear LDS dest (B region)
    }

    // --- read bases: everything else is a compile-time immediate.
    // A block (g,s) at g*2048 + s*1024; wave's g = (wave>>2)*4 + i.
    // B block (h,s) at ATILE + h*2048 + s*1024; wave's h = (wave&3)*2 + j.
    const signed char* rbA = &S[(wave >> 2) * 8192 + lane * 16];
    const signed char* rbB = &S[ATILE + (wave & 3) * 4096 + lane * 16];

    v16i acc[4][2] = {};
    v4i fa0[4], fb0[2];                 // s=0 fragment set
    v4i fa1[4], fb1[2];                 // s=1 fragment set

#define STAGE(P) do {                                                          \
        async16(ga[0], &S[(P) * BUFSZ + ldsA[0]]); ga[0] += BK;                \
        async16(ga[1], &S[(P) * BUFSZ + ldsA[1]]); ga[1] += BK;                \
        async16(gb[0], &S[(P) * BUFSZ + ldsB[0]]); gb[0] += BK;                \
        async16(gb[1], &S[(P) * BUFSZ + ldsB[1]]); gb[1] += BK;                \
    } while (0)

#define RD_S0(P) do {                                                          \
        fa0[0] = *(const v4i*)(rbA + (P) * BUFSZ + 0 * 2048);                  \
        fa0[1] = *(const v4i*)(rbA + (P) * BUFSZ + 1 * 2048);                  \
        fa0[2] = *(const v4i*)(rbA + (P) * BUFSZ + 2 * 2048);                  \
        fa0[3] = *(const v4i*)(rbA + (P) * BUFSZ + 3 * 2048);                  \
        fb0[0] = *(const v4i*)(rbB + (P) * BUFSZ + 0 * 2048);                  \
        fb0[1] = *(const v4i*)(rbB + (P) * BUFSZ + 1 * 2048);                  \
    } while (0)

#define RD_S1(P) do {                                                          \
        fa1[0] = *(const v4i*)(rbA + (P) * BUFSZ + 0 * 2048 + 1024);           \
        fa1[1] = *(const v4i*)(rbA + (P) * BUFSZ + 1 * 2048 + 1024);           \
        fa1[2] = *(const v4i*)(rbA + (P) * BUFSZ + 2 * 2048 + 1024);           \
        fa1[3] = *(const v4i*)(rbA + (P) * BUFSZ + 3 * 2048 + 1024);           \
        fb1[0] = *(const v4i*)(rbB + (P) * BUFSZ + 0 * 2048 + 1024);           \
        fb1[1] = *(const v4i*)(rbB + (P) * BUFSZ + 1 * 2048 + 1024);           \
    } while (0)

#define MFMA8(FA, FB) do {                                                     \
        __builtin_amdgcn_s_setprio(1);                                         \
        acc[0][0] = __builtin_amdgcn_mfma_i32_32x32x32_i8(FA[0], FB[0], acc[0][0], 0, 0, 0); \
        acc[0][1] = __builtin_amdgcn_mfma_i32_32x32x32_i8(FA[0], FB[1], acc[0][1], 0, 0, 0); \
        acc[1][0] = __builtin_amdgcn_mfma_i32_32x32x32_i8(FA[1], FB[0], acc[1][0], 0, 0, 0); \
        acc[1][1] = __builtin_amdgcn_mfma_i32_32x32x32_i8(FA[1], FB[1], acc[1][1], 0, 0, 0); \
        acc[2][0] = __builtin_amdgcn_mfma_i32_32x32x32_i8(FA[2], FB[0], acc[2][0], 0, 0, 0); \
        acc[2][1] = __builtin_amdgcn_mfma_i32_32x32x32_i8(FA[2], FB[1], acc[2][1], 0, 0, 0); \
        acc[3][0] = __builtin_amdgcn_mfma_i32_32x32x32_i8(FA[3], FB[0], acc[3][0], 0, 0, 0); \
        acc[3][1] = __builtin_amdgcn_mfma_i32_32x32x32_i8(FA[3], FB[1], acc[3][1], 0, 0, 0); \
        __builtin_amdgcn_s_setprio(0);                                         \
    } while (0)

    // One substep: compute tile P (s0 frags preloaded), pre-read tile PN's
    // s0 frags mid-substep (PN landed: VMCNT(4) with 3-deep staging).
#define SUBSTEP(P, PN, SP, VN) do {                                            \
        VMCNT(VN); BARRIER();        /* tile P..P+1 landed; buf SP free */     \
        STAGE(SP);                                                             \
        RD_S1(P);                    /* hides under the s0 MFMAs */            \
        MFMA8(fa0, fb0);             /* s0 of tile P (read last substep) */    \
        RD_S0(PN);                   /* reuses fa0/fb0 regs (lifetimes dj) */  \
        MFMA8(fa1, fb1);             /* s1 of tile P */                        \
    } while (0)

#define SUBSTEP_NS(P, PN, VN) do {                                             \
        VMCNT(VN); BARRIER();                                                  \
        RD_S1(P);                                                              \
        MFMA8(fa0, fb0);                                                       \
        RD_S0(PN);                                                             \
        MFMA8(fa1, fb1);                                                       \
    } while (0)

    // 64 K-tiles, tile t -> buf t&3.  Prologue stages 0,1,2; preloads s0(0).
    STAGE(0); STAGE(1); STAGE(2);
    VMCNT(8); BARRIER();             // tile 0 landed everywhere
    RD_S0(0);
    #pragma unroll 1
    for (int it = 0; it < 15; ++it) {
        SUBSTEP(0, 1, 3, 4);         // compute 4it+0, stage 4it+3
        SUBSTEP(1, 2, 0, 4);         // compute 4it+1, stage 4it+4
        SUBSTEP(2, 3, 1, 4);         // compute 4it+2, stage 4it+5
        SUBSTEP(3, 0, 2, 4);         // compute 4it+3, stage 4it+6
    }
    SUBSTEP(0, 1, 3, 4);             // compute 60, stage 63
    SUBSTEP_NS(1, 2, 4);             // compute 61 (62,63 in flight)
    SUBSTEP_NS(2, 3, 0);             // compute 62 (63 landed)
    // last tile: no next-tile pre-read
    RD_S1(3);
    MFMA8(fa0, fb0);
    MFMA8(fa1, fb1);                 // compute 63

#undef SUBSTEP
#undef SUBSTEP_NS
#undef STAGE
#undef RD_S0
#undef RD_S1
#undef MFMA8

    // epilogue: out[n,o] = acc * sx[n] * ws[o] + bias[o]
    // C/D: col = lane&31, row = (reg&3) + 8*(reg>>2) + 4*(lane>>5)  [m74/m101]
    #pragma unroll
    for (int j = 0; j < 2; ++j) {
        const int col = bn * BM + wn + j * 32 + l31;
        const float ws = wscale[col];
        const float bs = bias[col];
        #pragma unroll
        for (int i = 0; i < 4; ++i) {
            const int rb = bm * BM + wm + i * 32 + 4 * lh;
            #pragma unroll
            for (int r = 0; r < 16; ++r) {
                const int row = rb + (r & 3) + 8 * (r >> 2);
                out[(size_t)row * DIM + col] =
                    ((float)acc[i][j][r] * rowScale[row]) * ws + bs;
            }
        }
    }
}

// ---------------------------------------------------------------------------
extern "C" void kernel_launch(void* const* d_in, const int* in_sizes, int n_in,
                              void* d_out, int out_size, void* d_ws, size_t ws_size,
                              hipStream_t stream) {
    const float* x      = (const float*)d_in[0];
    const int*   wint   = (const int*)d_in[1];
    const float* wscale = (const float*)d_in[2];
    const float* bias   = (const float*)d_in[3];
    float* out = (float*)d_out;

    signed char* q8 = (signed char*)d_ws;                         // 16 MB
    signed char* w8 = q8 + (size_t)DIM * DIM;                     // 16 MB
    float* sx = (float*)(w8 + (size_t)DIM * DIM);                 // 16 KB

    prep<<<4096 + 16384, 256, 0, stream>>>(x, wint, q8, w8, sx);
    gemm_q8<<<dim3(DIM / BM, DIM / BM), 512, 0, stream>>>(q8, w8, sx, wscale, bias, out);
}